// Round 3
// baseline (1237.031 us; speedup 1.0000x reference)
//
#include <hip/hip_runtime.h>
#include <stdint.h>

typedef __bf16 bf16x8 __attribute__((ext_vector_type(8)));
typedef float f32x4 __attribute__((ext_vector_type(4)));

#define MFMA16(A, B, C) __builtin_amdgcn_mfma_f32_16x16x32_bf16((A), (B), (C), 0, 0, 0)

__device__ __forceinline__ float b2f(unsigned short u) {
    union { unsigned int i; float f; } v; v.i = ((unsigned int)u) << 16; return v.f;
}
__device__ __forceinline__ unsigned short f2b(float f) {
    union { float f; unsigned int i; } v; v.f = f;
    unsigned int x = v.i;
    return (unsigned short)((x + 0x7FFFu + ((x >> 16) & 1u)) >> 16);
}
__device__ __forceinline__ float ldf(const void* p, long i, int isbf) {
    return isbf ? b2f(((const unsigned short*)p)[i]) : ((const float*)p)[i];
}

// Probe storage dtype (bf16 vs f32) of float arrays, and idx width (i32 vs i64).
__global__ void k_probe(const unsigned int* __restrict__ wq,
                        const unsigned int* __restrict__ idxw, int* __restrict__ flags) {
    if (threadIdx.x == 0) {
        int ok = 0;
        for (int i = 0; i < 8; i++) {
            unsigned int e = (wq[i] >> 7) & 0xFFu;
            if (e >= 0x60u && e <= 0x7Cu) ok++;
        }
        flags[0] = (ok == 8) ? 1 : 0;
        int z = 0, lr = 0;
        for (int i = 0; i < 4; i++) {
            if (idxw[2 * i + 1] == 0u) z++;
            if (idxw[2 * i] < 0x4000000u) lr++;
        }
        flags[1] = (z == 4 && lr == 4) ? 1 : 0;
    }
}

// Q[c] = S . Wq[c,:] + bq[c]; decode prelu_a
__global__ void k_q(const void* __restrict__ S, const void* __restrict__ Wq,
                    const void* __restrict__ bq, const void* __restrict__ prelu,
                    const int* __restrict__ flags, float* __restrict__ Q,
                    float* __restrict__ pf) {
    int isbf = flags[0];
    int c = threadIdx.x;
    float acc = 0.f;
    for (int j = 0; j < 256; j++) acc += ldf(S, j, isbf) * ldf(Wq, (long)c * 256 + j, isbf);
    Q[c] = acc + ldf(bq, c, isbf);
    if (c == 0)
        pf[0] = isbf ? b2f(((const unsigned short*)prelu)[0]) : ((const float*)prelu)[0];
}

// qkb[h,j] = (Wk[h*64:,j] . Q_h)/16 (bf16; rows 4..15 zero); qb[h] = (bk_h . Q_h)/16
__global__ void k_qk(const void* __restrict__ Wk, const void* __restrict__ bk,
                     const float* __restrict__ Q, const int* __restrict__ flags,
                     unsigned short* __restrict__ qkb, float* __restrict__ qb) {
    int isbf = flags[0];
    int h = blockIdx.x, j = threadIdx.x;
    float acc = 0.f;
    if (h < 4) {
        for (int d = 0; d < 64; d++) acc += ldf(Wk, (long)(h * 64 + d) * 256 + j, isbf) * Q[h * 64 + d];
        acc *= 0.0625f;
    }
    qkb[h * 256 + j] = f2b(acc);
    if (j == 0) {
        float s = 0.f;
        if (h < 4) {
            for (int d = 0; d < 64; d++) s += ldf(bk, h * 64 + d, isbf) * Q[h * 64 + d];
            s *= 0.0625f;
        }
        qb[h] = s;
    }
}

// Convert Wv, Wo to bf16 scratch.
__global__ void k_cvt(const void* __restrict__ Wv, const void* __restrict__ Wo,
                      const int* __restrict__ flags, unsigned short* __restrict__ Wvb,
                      unsigned short* __restrict__ Wob) {
    int isbf = flags[0];
    long i = (long)blockIdx.x * 256 + threadIdx.x;
    const void* src = (i < 65536) ? Wv : Wo;
    unsigned short* dst = (i < 65536) ? Wvb : Wob;
    long k = (i < 65536) ? i : i - 65536;
    dst[k] = isbf ? ((const unsigned short*)src)[k] : f2b(((const float*)src)[k]);
}

// k_v: stage x->LDS bf16; scores MFMA -> e, denom atomics; V = x@WvT via MFMA;
// scatter e[n, head(c)] * V[n,c] into vagg with f32 atomics.
__global__ __launch_bounds__(256) void k_v(
    const void* __restrict__ x, const int* __restrict__ idxp,
    const unsigned short* __restrict__ Wvb, const unsigned short* __restrict__ qkb,
    const float* __restrict__ qb, const int* __restrict__ flags,
    float* __restrict__ denom, float* __restrict__ vagg, int N) {
    __shared__ unsigned short xs[128 * 264];
    __shared__ float es[128][4];
    int isbf = flags[0], is64 = flags[1];
    int tid = threadIdx.x;
    long base = (long)blockIdx.x * 128;

    // stage 128x256 x tile as bf16
#pragma unroll
    for (int ch = 0; ch < 16; ch++) {
        int i16 = tid + ch * 256;
        int row = i16 >> 5;
        int col = (i16 & 31) * 8;
        long grow = base + row;
        uint4 t;
        if (grow < N) {
            if (isbf) {
                t = *(const uint4*)((const unsigned short*)x + grow * 256 + col);
            } else {
                const float* xp = (const float*)x + grow * 256 + col;
                float4 a = *(const float4*)xp;
                float4 b = *(const float4*)(xp + 4);
                t.x = (unsigned int)f2b(a.x) | ((unsigned int)f2b(a.y) << 16);
                t.y = (unsigned int)f2b(a.z) | ((unsigned int)f2b(a.w) << 16);
                t.z = (unsigned int)f2b(b.x) | ((unsigned int)f2b(b.y) << 16);
                t.w = (unsigned int)f2b(b.z) | ((unsigned int)f2b(b.w) << 16);
            }
        } else {
            t.x = t.y = t.z = t.w = 0u;
        }
        *(uint4*)&xs[row * 264 + col] = t;
    }
    __syncthreads();

    int w = tid >> 6, l = tid & 63;
    int m = l & 15, q = l >> 4;

    // POI ids for this lane's D rows
    int ids[2][4];
#pragma unroll
    for (int g2 = 0; g2 < 2; g2++)
#pragma unroll
        for (int r = 0; r < 4; r++) {
            long gr = base + w * 32 + g2 * 16 + q * 4 + r;
            ids[g2][r] = (gr < N) ? (is64 ? idxp[gr << 1] : idxp[gr]) : 0;
        }

    // A fragments (hoisted: reused for scores and all 16 V tiles)
    bf16x8 a[2][8];
#pragma unroll
    for (int g2 = 0; g2 < 2; g2++)
#pragma unroll
        for (int s = 0; s < 8; s++)
            a[g2][s] = *(const bf16x8*)&xs[(w * 32 + g2 * 16 + m) * 264 + q * 8 + s * 32];

    // scores -> e -> denom atomics
    {
        const bf16x8* qkp = (const bf16x8*)(qkb + (size_t)m * 256);
        bf16x8 qf[8];
#pragma unroll
        for (int s = 0; s < 8; s++) qf[s] = qkp[q + s * 4];
        float qbm = qb[m & 3];
#pragma unroll
        for (int g2 = 0; g2 < 2; g2++) {
            f32x4 sacc = {0.f, 0.f, 0.f, 0.f};
#pragma unroll
            for (int s = 0; s < 8; s++) sacc = MFMA16(a[g2][s], qf[s], sacc);
            if (m < 4) {
#pragma unroll
                for (int r = 0; r < 4; r++) {
                    int row = w * 32 + g2 * 16 + q * 4 + r;
                    long gr = base + row;
                    float e = 0.f;
                    if (gr < N) {
                        e = __expf(sacc[r] + qbm);  // |score| << 1: shift-free is safe
                        unsafeAtomicAdd(&denom[(long)ids[g2][r] * 4 + m], e);
                    }
                    es[row][m] = e;
                }
            }
        }
    }
    // es: written and read by the same wave only -> no barrier needed

    // V tiles + e-weighted scatter (head = t>>2 — the OUTPUT channel's head)
#pragma unroll 1
    for (int t = 0; t < 16; t++) {
        int h_t = t >> 2;
        const bf16x8* wvp = (const bf16x8*)(Wvb + (size_t)(t * 16 + m) * 256);
        bf16x8 b[8];
#pragma unroll
        for (int s = 0; s < 8; s++) b[s] = wvp[q + s * 4];
#pragma unroll
        for (int g2 = 0; g2 < 2; g2++) {
            f32x4 acc = {0.f, 0.f, 0.f, 0.f};
#pragma unroll
            for (int s = 0; s < 8; s++) acc = MFMA16(a[g2][s], b[s], acc);
#pragma unroll
            for (int r = 0; r < 4; r++) {
                int row = w * 32 + g2 * 16 + q * 4 + r;
                long gr = base + row;
                if (gr < N) {
                    float val = acc[r] * es[row][h_t];
                    unsafeAtomicAdd(&vagg[(long)ids[g2][r] * 256 + t * 16 + m], val);
                }
            }
        }
    }
}

// k_out: O = Q + (vagg + bv*den)/(den+1e-16)  [O kept f32 in LDS];
//        out = prelu(O + relu(O@WoT + bo))
__global__ __launch_bounds__(256) void k_out(
    const float* __restrict__ Q, const float* __restrict__ denom,
    const float* __restrict__ vagg, const void* __restrict__ bv,
    const unsigned short* __restrict__ Wob, const void* __restrict__ bo,
    const float* __restrict__ pf, const int* __restrict__ flags,
    void* __restrict__ out, int P) {
    __shared__ float Os[4][16 * 264];
    int isbf = flags[0];
    int tid = threadIdx.x;
    int w = tid >> 6, l = tid & 63;
    int m = l & 15, q = l >> 4;
    long pbase = (long)blockIdx.x * 64 + w * 16;
    float aP = pf[0];
    long pm = pbase + m;
    bool vm = pm < P;

    float den4[4], rd4[4];
#pragma unroll
    for (int h = 0; h < 4; h++) {
        float d = vm ? denom[pm * 4 + h] : 0.f;
        den4[h] = d;
        rd4[h] = 1.0f / (d + 1e-16f);
    }

    bf16x8 of[8];
#pragma unroll
    for (int s = 0; s < 8; s++) {
        int c0 = q * 8 + s * 32;
        int h = s >> 1;  // head of the 8 contiguous channels c0..c0+7
        bf16x8 ov;
        if (vm) {
            const float* ag = vagg + pm * 256 + c0;
#pragma unroll
            for (int j = 0; j < 8; j++) {
                float o = Q[c0 + j] + (ag[j] + ldf(bv, c0 + j, isbf) * den4[h]) * rd4[h];
                Os[w][m * 264 + c0 + j] = o;
                ov[j] = (__bf16)o;
            }
        } else {
#pragma unroll
            for (int j = 0; j < 8; j++) { Os[w][m * 264 + c0 + j] = 0.f; ov[j] = (__bf16)0.0f; }
        }
        of[s] = ov;
    }
    // Os: same-wave write/read only -> no barrier needed

#pragma unroll 1
    for (int t = 0; t < 16; t++) {
        const bf16x8* wop = (const bf16x8*)(Wob + (size_t)(t * 16 + m) * 256);
        f32x4 acc = {0.f, 0.f, 0.f, 0.f};
#pragma unroll
        for (int s = 0; s < 8; s++) acc = MFMA16(of[s], wop[q + s * 4], acc);
        int c = t * 16 + m;
        float boc = ldf(bo, c, isbf);
#pragma unroll
        for (int r = 0; r < 4; r++) {
            int row = q * 4 + r;
            long p = pbase + row;
            if (p < P) {
                float Ov = Os[w][row * 264 + c];
                float lin = fmaxf(acc[r] + boc, 0.f);
                float res = Ov + lin;
                res = (res >= 0.f) ? res : aP * res;
                if (res != res) res = 0.f;
                if (isbf) ((unsigned short*)out)[p * 256 + c] = f2b(res);
                else      ((float*)out)[p * 256 + c] = res;
            }
        }
    }
}

extern "C" void kernel_launch(void* const* d_in, const int* in_sizes, int n_in,
                              void* d_out, int out_size, void* d_ws, size_t ws_size,
                              hipStream_t stream) {
    const void* x  = d_in[0];
    const int* idx = (const int*)d_in[1];
    const void* Wq = d_in[3];
    const void* bq = d_in[4];
    const void* Wk = d_in[5];
    const void* bk = d_in[6];
    const void* Wv = d_in[7];
    const void* bv = d_in[8];
    const void* Wo = d_in[9];
    const void* bo = d_in[10];
    const void* S  = d_in[11];
    const void* pr = d_in[12];

    int N = in_sizes[0] / 256;
    int P = out_size / 256;

    float* ws = (float*)d_ws;
    int* flags          = (int*)ws;                          // 2 ints
    float* pf           = ws + 2;                            // 1
    float* Q            = ws + 16;                           // 256
    float* qb           = ws + 272;                          // 16
    unsigned short* qkb = (unsigned short*)(ws + 288);       // 16*256 bf16
    unsigned short* Wvb = (unsigned short*)(ws + 2336);      // 65536 bf16
    unsigned short* Wob = (unsigned short*)(ws + 35104);     // 65536 bf16
    float* denom        = ws + 67872;                        // P*4
    float* vagg         = denom + (size_t)P * 4;             // P*256

    size_t need = (67872 + (size_t)P * 260) * sizeof(float);
    if (ws_size < need) return;

    hipMemsetAsync(denom, 0, (size_t)P * 260 * sizeof(float), stream);

    k_probe<<<1, 64, 0, stream>>>((const unsigned int*)Wq, (const unsigned int*)idx, flags);
    k_q<<<1, 256, 0, stream>>>(S, Wq, bq, pr, flags, Q, pf);
    k_qk<<<16, 256, 0, stream>>>(Wk, bk, Q, flags, qkb, qb);
    k_cvt<<<512, 256, 0, stream>>>(Wv, Wo, flags, Wvb, Wob);
    k_v<<<(N + 127) / 128, 256, 0, stream>>>(x, idx, Wvb, qkb, qb, flags, denom, vagg, N);
    k_out<<<(P + 63) / 64, 256, 0, stream>>>(Q, denom, vagg, bv, Wob, bo, pf, flags, d_out, P);
}